// Round 12
// baseline (156.523 us; speedup 1.0000x reference)
//
#include <hip/hip_runtime.h>

// Problem: B=8, L=1024, C=384, H=6, D=64, K=2(radial), N=4(angular)
// R11: MFMA GEMMs (verified) + barrier-free swapped-QK^T attention with
//      4-way key split (12288 waves), LDS=20480 (8 blocks/CU), VGPR<=64.
typedef unsigned int  u32;
typedef unsigned short u16;
typedef __attribute__((ext_vector_type(8))) short short8;   // 8 bf16
typedef __attribute__((ext_vector_type(4))) float f32x4;

__device__ __forceinline__ u16 f2bf(float x) {
  union { float f; u32 u; } un; un.f = x;
  u32 r = un.u + 0x7FFFu + ((un.u >> 16) & 1u);   // RNE
  return (u16)(r >> 16);
}
__device__ __forceinline__ u32 cvtpk(float lo, float hi) {   // 2xf32 -> packed bf16
  u32 r;
  asm("v_cvt_pk_bf16_f32 %0, %1, %2" : "=v"(r) : "v"(lo), "v"(hi));
  return r;
}
__device__ __forceinline__ f32x4 mfma_bf16(short8 a, short8 b, f32x4 c) {
  return __builtin_amdgcn_mfma_f32_16x16x32_bf16(a, b, c, 0, 0, 0);
}

// ---------------- prep: RMSNorm -> xn(bf16), convert w_in/w_out -> bf16 ----
__global__ __launch_bounds__(256) void prep_kernel(
    const float* __restrict__ x, const float* __restrict__ w_norm,
    const float* __restrict__ w_in, const float* __restrict__ w_out,
    u16* __restrict__ xn, u16* __restrict__ winb, u16* __restrict__ woutb)
{
  int blk = blockIdx.x, t = threadIdx.x;
  if (blk < 2048) {               // 8192 rows, 4 rows/block (1 per wave)
    int wv = t >> 6, lane = t & 63;
    int row = blk * 4 + wv;
    const float* xr = x + (size_t)row * 384;
    float v[6]; float ss = 0.f;
    #pragma unroll
    for (int i = 0; i < 6; i++) { v[i] = xr[lane + 64 * i]; ss += v[i] * v[i]; }
    #pragma unroll
    for (int off = 32; off > 0; off >>= 1) ss += __shfl_xor(ss, off);
    float rs = __builtin_amdgcn_rsqf(ss * (1.0f / 384.0f) + 1e-5f);
    #pragma unroll
    for (int i = 0; i < 6; i++) {
      float xv = v[i] * rs * w_norm[lane + 64 * i];
      xn[(size_t)row * 384 + lane + 64 * i] = f2bf(xv);
    }
  } else {                        // weight conversion: 442368 + 147456
    int base = (blk - 2048) * 2048 + t * 8;
    #pragma unroll
    for (int j = 0; j < 8; j++) {
      int idx = base + j;
      if (idx < 442368) winb[idx] = f2bf(w_in[idx]);
      else              woutb[idx - 442368] = f2bf(w_out[idx - 442368]);
    }
  }
}

// ---------------- MFMA GEMM: out[M,.] = A[M,K](lda)*Bw[N,K](ldb)^T + bias --
// 128x128 tile, BK=64, 4 waves (2x2), 16x16x32 bf16 MFMA, padded LDS. VERIFIED.
template<bool OUT_F32, bool QSCALE>
__global__ __launch_bounds__(256) void gemm_kernel(
    const u16* __restrict__ A, int lda,
    const u16* __restrict__ Bw, int ldb,
    const float* __restrict__ bias, void* __restrict__ outp, int ldc, int K)
{
  __shared__ __attribute__((aligned(16))) u16 As[128 * 72];
  __shared__ __attribute__((aligned(16))) u16 Bs[128 * 72];
  int t = threadIdx.x;
  int lane = t & 63, wv = t >> 6;
  int g = lane >> 4, cl = lane & 15;
  int row0 = blockIdx.x * 128, col0 = blockIdx.y * 128;
  int wm = (wv >> 1) * 64, wn = (wv & 1) * 64;
  f32x4 acc[4][4];
  #pragma unroll
  for (int i = 0; i < 4; i++)
    #pragma unroll
    for (int j = 0; j < 4; j++) acc[i][j] = (f32x4){0.f, 0.f, 0.f, 0.f};

  for (int k0 = 0; k0 < K; k0 += 64) {
    __syncthreads();
    #pragma unroll
    for (int j = 0; j < 4; j++) {
      int i = t + 256 * j;
      int r = i >> 3, ch = i & 7;
      *(uint4*)(&As[r * 72 + ch * 8]) =
          *(const uint4*)(A + (size_t)(row0 + r) * lda + k0 + ch * 8);
      *(uint4*)(&Bs[r * 72 + ch * 8]) =
          *(const uint4*)(Bw + (size_t)(col0 + r) * ldb + k0 + ch * 8);
    }
    __syncthreads();
    #pragma unroll
    for (int kh = 0; kh < 2; kh++) {
      short8 af[4], bfr[4];
      #pragma unroll
      for (int s = 0; s < 4; s++) {
        af[s]  = *(const short8*)(&As[(wm + s * 16 + cl) * 72 + kh * 32 + g * 8]);
        bfr[s] = *(const short8*)(&Bs[(wn + s * 16 + cl) * 72 + kh * 32 + g * 8]);
      }
      #pragma unroll
      for (int i = 0; i < 4; i++)
        #pragma unroll
        for (int j = 0; j < 4; j++)
          acc[i][j] = mfma_bf16(af[i], bfr[j], acc[i][j]);
    }
  }
  // epilogue: C/D layout col=lane&15, row=4*(lane>>4)+r  [HW-verified R4]
  #pragma unroll
  for (int i = 0; i < 4; i++) {
    #pragma unroll
    for (int j = 0; j < 4; j++) {
      int colb = col0 + wn + j * 16 + cl;
      float bv = bias[colb];
      #pragma unroll
      for (int r = 0; r < 4; r++) {
        int rowb = row0 + wm + i * 16 + g * 4 + r;
        float v = acc[i][j][r] + bv;
        if (QSCALE) { if (colb < 384) v *= 0.125f; }   // fold 1/sqrt(D) into Q
        if (OUT_F32) ((float*)outp)[(size_t)rowb * ldc + colb] = v;
        else ((u16*)outp)[(size_t)rowb * ldc + colb] = f2bf(v);
      }
    }
  }
}

// ---------------- barrier-free swapped-QK^T attention, 4-way key split -----
// Block = (b, h, 16 q-rows), 256 threads / 4 waves; wave wv owns key quarter
// [wv*256, +256) in 8 tiles of 32 keys. Per tile (in-wave, NO barriers):
//   V-stage to wave-private vsmem[wv] (permuted slots), swapped QK^T MFMA,
//   Chebyshev bias, defer-max softmax (no cross-lane in common path), PV MFMA.
// End: per-lane l reduce, 4-quarter merge via LDS overlay (R4/R8-verified).
__global__ __launch_bounds__(256) void attn_swap4(
    const u16* __restrict__ qkv, const float* __restrict__ pos,
    const float* __restrict__ bcf, const float* __restrict__ ccf,
    u16* __restrict__ obuf)
{
  __shared__ __attribute__((aligned(16))) u16 vsmem[4][64][40];  // 20480 B total

  // XCD-aware remap: all 64 q-strips of one (b,h) share bid%8 -> same XCD L2.
  int bid = blockIdx.x;                       // 3072 = 8 * 384
  int xslot = bid & 7, rest = bid >> 3;
  int qt16 = rest & 63, gdiv = rest >> 6;     // gdiv in [0,6)
  int g48 = gdiv * 8 + xslot;                 // (b*6 + h) in [0,48)
  int b = g48 / 6, h = g48 - b * 6;

  int t = threadIdx.x, lane = t & 63, wv = t >> 6;   // wv = key quarter
  int g = lane >> 4, cl = lane & 15;

  float bc[15], cc[15];                        // block-uniform
  #pragma unroll
  for (int i = 0; i < 15; i++) { bc[i] = bcf[h * 15 + i]; cc[i] = ccf[h * 15 + i]; }

  // Q B-frag (col=cl=q, k=dim 8g+j); Q pre-scaled by 1/8 in GEMM1
  int qrow = qt16 * 16 + cl;
  const u16* qbase = qkv + (size_t)(b * 1024 + qrow) * 1152 + h * 64;
  short8 qf0 = *(const short8*)(qbase + g * 8);
  short8 qf1 = *(const short8*)(qbase + 32 + g * 8);
  float qx = pos[(size_t)(b * 1024 + qrow) * 2 + 0];
  float qy = pos[(size_t)(b * 1024 + qrow) * 2 + 1];

  f32x4 oa[4];
  #pragma unroll
  for (int d = 0; d < 4; d++) oa[d] = (f32x4){0.f, 0.f, 0.f, 0.f};
  float m_own = -1e30f, l_own = 0.f;           // q=cl; l is PER-LANE partial

  const u16* kb = qkv + (size_t)b * 1024 * 1152 + 384 + h * 64;
  int kappa = lane & 31, dh = lane >> 5;       // V-stage identity
  const u16* vb = qkv + (size_t)b * 1024 * 1152 + 768 + h * 64 + dh * 32;
  const float* pb = pos + (size_t)b * 2048;

  // key kappa(=16s+4G+r) -> physical slot 8G+4s+r (matches P frag order)
  int pcol = (kappa & 3) | ((kappa & 0x0C) << 1) | ((kappa & 0x10) >> 2);
  u16* vdst = &vsmem[wv][dh * 32][0] + pcol;   // row stride 40 u16

  // u32 element offsets, incremented per tile (kb/vb/pb are uniform bases)
  u32 koff = (u32)(wv * 256 + cl) * 1152;      // + ks*16*1152 per ks
  u32 voff = (u32)(wv * 256 + kappa) * 1152;
  u32 poff = (u32)(wv * 256 + 4 * g) * 2;      // + ks*32 per ks

  for (int it = 0; it < 8; it++) {
    // ---- V-stage (wave-private; in-wave DS ordering, no barrier) ----
    {
      const u16* vr = vb + voff;
      uint4 a0 = *(const uint4*)(vr);
      uint4 a1 = *(const uint4*)(vr + 8);
      uint4 a2 = *(const uint4*)(vr + 16);
      uint4 a3 = *(const uint4*)(vr + 24);
      #define ST(i, val) vdst[(i) * 40] = (u16)(val)
      ST(0,  a0.x); ST(1,  a0.x >> 16); ST(2,  a0.y); ST(3,  a0.y >> 16);
      ST(4,  a0.z); ST(5,  a0.z >> 16); ST(6,  a0.w); ST(7,  a0.w >> 16);
      ST(8,  a1.x); ST(9,  a1.x >> 16); ST(10, a1.y); ST(11, a1.y >> 16);
      ST(12, a1.z); ST(13, a1.z >> 16); ST(14, a1.w); ST(15, a1.w >> 16);
      ST(16, a2.x); ST(17, a2.x >> 16); ST(18, a2.y); ST(19, a2.y >> 16);
      ST(20, a2.z); ST(21, a2.z >> 16); ST(22, a2.w); ST(23, a2.w >> 16);
      ST(24, a3.x); ST(25, a3.x >> 16); ST(26, a3.y); ST(27, a3.y >> 16);
      ST(28, a3.z); ST(29, a3.z >> 16); ST(30, a3.w); ST(31, a3.w >> 16);
      #undef ST
    }
    // ---- swapped QK^T: sk[ks][r] = S[key slot][q=cl] ----
    f32x4 sk[2];
    #pragma unroll
    for (int ks = 0; ks < 2; ks++) {
      const u16* kr = kb + koff + ks * (16 * 1152);
      short8 kf0 = *(const short8*)(kr + g * 8);
      short8 kf1 = *(const short8*)(kr + 32 + g * 8);
      f32x4 z = (f32x4){0.f, 0.f, 0.f, 0.f};
      z = mfma_bf16(kf0, qf0, z);
      z = mfma_bf16(kf1, qf1, z);
      sk[ks] = z;
    }
    // ---- polar bias: Chebyshev recurrence, Horner in r ----
    #pragma unroll
    for (int ks = 0; ks < 2; ks++) {
      float4 pA = *(const float4*)(pb + poff + ks * 32);
      float4 pB = *(const float4*)(pb + poff + ks * 32 + 4);
      float kxs[4] = {pA.x, pA.z, pB.x, pB.z};
      float kys[4] = {pA.y, pA.w, pB.y, pB.w};
      #pragma unroll
      for (int r = 0; r < 4; r++) {
        float dx = qx - kxs[r], dy = qy - kys[r];
        float r2 = dx * dx + dy * dy;
        bool zz = !(r2 > 0.f);
        float ir = zz ? 0.f : __builtin_amdgcn_rsqf(r2);
        float rr = r2 * ir;
        float c1 = zz ? 1.f : dx * ir;
        float s1 = dy * ir;
        float tc = c1 + c1;
        float c2 = __builtin_fmaf(tc, c1, -1.f), s2 = tc * s1;
        float c3 = __builtin_fmaf(tc, c2, -c1),  s3 = __builtin_fmaf(tc, s2, -s1);
        float c4 = __builtin_fmaf(tc, c3, -c2),  s4 = __builtin_fmaf(tc, s3, -s2);
        float a0 = bc[0] + bc[1]*c1 + bc[2]*c2 + bc[3]*c3 + bc[4]*c4
                 + cc[1]*s1 + cc[2]*s2 + cc[3]*s3 + cc[4]*s4;
        float a1 = bc[5] + bc[6]*c1 + bc[7]*c2 + bc[8]*c3 + bc[9]*c4
                 + cc[6]*s1 + cc[7]*s2 + cc[8]*s3 + cc[9]*s4;
        float a2 = bc[10] + bc[11]*c1 + bc[12]*c2 + bc[13]*c3 + bc[14]*c4
                 + cc[11]*s1 + cc[12]*s2 + cc[13]*s3 + cc[14]*s4;
        sk[ks][r] += a0 + rr * __builtin_fmaf(rr, a2, a1);
      }
    }
    koff += 32 * 1152; voff += 32 * 1152; poff += 64;
    // ---- defer-max online softmax: common path = no cross-lane ops ----
    float tmax = -1e30f;
    #pragma unroll
    for (int ks = 0; ks < 2; ks++)
      #pragma unroll
      for (int r = 0; r < 4; r++) tmax = fmaxf(tmax, sk[ks][r]);
    if (!__all((int)(tmax <= m_own + 8.f))) {
      tmax = fmaxf(tmax, __shfl_xor(tmax, 16));
      tmax = fmaxf(tmax, __shfl_xor(tmax, 32));
      float mn = fmaxf(m_own, tmax);
      float sc = __builtin_amdgcn_exp2f((m_own - mn) * 1.44269504f);
      m_own = mn;
      l_own *= sc;
      #pragma unroll
      for (int r = 0; r < 4; r++) {
        float scr = __shfl(sc, 4 * g + r);     // rescale rows q=4g+r
        #pragma unroll
        for (int d = 0; d < 4; d++) oa[d][r] *= scr;
      }
    }
    float psum = 0.f;
    #pragma unroll
    for (int ks = 0; ks < 2; ks++)
      #pragma unroll
      for (int r = 0; r < 4; r++) {
        float p = __builtin_amdgcn_exp2f((sk[ks][r] - m_own) * 1.44269504f);
        psum += p; sk[ks][r] = p;              // bounded by e^8
      }
    l_own += psum;                             // per-lane partial
    // P A-frag: element j holds key 16*(j>>2) + 4g + (j&3)
    union { u32 w[4]; short8 s8; } pk;
    pk.w[0] = cvtpk(sk[0][0], sk[0][1]); pk.w[1] = cvtpk(sk[0][2], sk[0][3]);
    pk.w[2] = cvtpk(sk[1][0], sk[1][1]); pk.w[3] = cvtpk(sk[1][2], sk[1][3]);
    // ---- PV MFMA: B-frag = vsmem rows (permuted slots match A) ----
    #pragma unroll
    for (int d = 0; d < 4; d++) {
      short8 vf = *(const short8*)(&vsmem[wv][d * 16 + cl][g * 8]);
      oa[d] = mfma_bf16(pk.s8, vf, oa[d]);
    }
  }
  // ---- row-reduce the per-lane partial l (once) ----
  l_own += __shfl_xor(l_own, 16);
  l_own += __shfl_xor(l_own, 32);
  __syncthreads();                             // all waves done with vsmem
  // ---- merge the 4 key quarters; overlay vsmem (o1: 12288 B, ml at tail) --
  float* o1 = (float*)&vsmem[0][0][0];         // [3][16][64] f32
  float* ml = (float*)((char*)&vsmem[0][0][0] + 19968);   // m[4][16], l[4][16]
  if (lane < 16) { ml[wv * 16 + lane] = m_own; ml[64 + wv * 16 + lane] = l_own; }
  if (wv > 0) {
    #pragma unroll
    for (int r = 0; r < 4; r++) {
      int row = 4 * g + r;
      #pragma unroll
      for (int d = 0; d < 4; d++)
        o1[((wv - 1) * 16 + row) * 64 + d * 16 + cl] = oa[d][r];
    }
  }
  __syncthreads();
  if (wv == 0) {
    float m1 = ml[16 + cl], m2 = ml[32 + cl], m3 = ml[48 + cl];
    float l1 = ml[80 + cl], l2 = ml[96 + cl], l3 = ml[112 + cl];
    float M  = fmaxf(fmaxf(m_own, m1), fmaxf(m2, m3));
    float f0 = __builtin_amdgcn_exp2f((m_own - M) * 1.44269504f);
    float f1 = __builtin_amdgcn_exp2f((m1 - M) * 1.44269504f);
    float f2 = __builtin_amdgcn_exp2f((m2 - M) * 1.44269504f);
    float f3 = __builtin_amdgcn_exp2f((m3 - M) * 1.44269504f);
    float linv = __builtin_amdgcn_rcpf(l_own * f0 + l1 * f1 + l2 * f2 + l3 * f3);
    #pragma unroll
    for (int r = 0; r < 4; r++) {
      int row = 4 * g + r;
      float f0r = __shfl(f0, row), f1r = __shfl(f1, row);
      float f2r = __shfl(f2, row), f3r = __shfl(f3, row);
      float invr = __shfl(linv, row);
      int qr = qt16 * 16 + row;
      #pragma unroll
      for (int d = 0; d < 4; d++) {
        float val = (oa[d][r] * f0r
                   + o1[(0 * 16 + row) * 64 + d * 16 + cl] * f1r
                   + o1[(1 * 16 + row) * 64 + d * 16 + cl] * f2r
                   + o1[(2 * 16 + row) * 64 + d * 16 + cl] * f3r) * invr;
        obuf[(size_t)(b * 1024 + qr) * 384 + h * 64 + d * 16 + cl] = f2bf(val);
      }
    }
  }
}

// ---------------- launch ---------------------------------------------------
extern "C" void kernel_launch(void* const* d_in, const int* in_sizes, int n_in,
                              void* d_out, int out_size, void* d_ws, size_t ws_size,
                              hipStream_t stream) {
  const float* x      = (const float*)d_in[0];
  const float* pos    = (const float*)d_in[1];
  const float* w_norm = (const float*)d_in[2];
  const float* w_in   = (const float*)d_in[3];
  const float* b_in   = (const float*)d_in[4];
  const float* w_out  = (const float*)d_in[5];
  const float* b_out  = (const float*)d_in[6];
  const float* b_coef = (const float*)d_in[7];
  const float* c_coef = (const float*)d_in[8];

  char* ws = (char*)d_ws;
  // ws layout (25.1 MB):
  //   [0, 6291456)        xn (bf16 8192x384); obuf overlays it (xn dead after GEMM1)
  //   [6291456, 7176192)  winb (bf16 1152x384)
  //   [7176192, 7471104)  woutb (bf16 384x384)
  //   [7471104, 26345472) qkv (bf16 8192x1152), Q pre-scaled by 1/8
  u16* xn    = (u16*)(ws + 0);
  u16* obuf  = (u16*)(ws + 0);          // overlays xn
  u16* winb  = (u16*)(ws + 6291456);
  u16* woutb = (u16*)(ws + 7176192);
  u16* qkvb  = (u16*)(ws + 7471104);

  prep_kernel<<<2336, 256, 0, stream>>>(x, w_norm, w_in, w_out, xn, winb, woutb);
  gemm_kernel<false, true><<<dim3(64, 9), 256, 0, stream>>>(
      xn, 384, winb, 384, b_in, qkvb, 1152, 384);
  attn_swap4<<<3072, 256, 0, stream>>>(qkvb, pos, b_coef, c_coef, obuf);
  gemm_kernel<true, false><<<dim3(64, 3), 256, 0, stream>>>(
      obuf, 384, woutb, 384, b_out, (float*)d_out, 384, 384);
}

// Round 13
// 146.869 us; speedup vs baseline: 1.0657x; 1.0657x over previous
//
#include <hip/hip_runtime.h>

// Problem: B=8, L=1024, C=384, H=6, D=64, K=2(radial), N=4(angular)
// R12: MFMA GEMMs (verified) + barrier-free swapped-QK^T attention with
//      software-pipelined tile loop (prefetch V/K/pos into regs, T14) and
//      packed-f32 (v_pk_fma) Chebyshev bias across the two key groups.
typedef unsigned int  u32;
typedef unsigned short u16;
typedef __attribute__((ext_vector_type(8))) short short8;   // 8 bf16
typedef __attribute__((ext_vector_type(4))) float f32x4;
typedef __attribute__((ext_vector_type(2))) float f32x2;

__device__ __forceinline__ u16 f2bf(float x) {
  union { float f; u32 u; } un; un.f = x;
  u32 r = un.u + 0x7FFFu + ((un.u >> 16) & 1u);   // RNE
  return (u16)(r >> 16);
}
__device__ __forceinline__ u32 cvtpk(float lo, float hi) {   // 2xf32 -> packed bf16
  u32 r;
  asm("v_cvt_pk_bf16_f32 %0, %1, %2" : "=v"(r) : "v"(lo), "v"(hi));
  return r;
}
__device__ __forceinline__ f32x4 mfma_bf16(short8 a, short8 b, f32x4 c) {
  return __builtin_amdgcn_mfma_f32_16x16x32_bf16(a, b, c, 0, 0, 0);
}

// ---------------- prep: RMSNorm -> xn(bf16), convert w_in/w_out -> bf16 ----
__global__ __launch_bounds__(256) void prep_kernel(
    const float* __restrict__ x, const float* __restrict__ w_norm,
    const float* __restrict__ w_in, const float* __restrict__ w_out,
    u16* __restrict__ xn, u16* __restrict__ winb, u16* __restrict__ woutb)
{
  int blk = blockIdx.x, t = threadIdx.x;
  if (blk < 2048) {               // 8192 rows, 4 rows/block (1 per wave)
    int wv = t >> 6, lane = t & 63;
    int row = blk * 4 + wv;
    const float* xr = x + (size_t)row * 384;
    float v[6]; float ss = 0.f;
    #pragma unroll
    for (int i = 0; i < 6; i++) { v[i] = xr[lane + 64 * i]; ss += v[i] * v[i]; }
    #pragma unroll
    for (int off = 32; off > 0; off >>= 1) ss += __shfl_xor(ss, off);
    float rs = __builtin_amdgcn_rsqf(ss * (1.0f / 384.0f) + 1e-5f);
    #pragma unroll
    for (int i = 0; i < 6; i++) {
      float xv = v[i] * rs * w_norm[lane + 64 * i];
      xn[(size_t)row * 384 + lane + 64 * i] = f2bf(xv);
    }
  } else {                        // weight conversion: 442368 + 147456
    int base = (blk - 2048) * 2048 + t * 8;
    #pragma unroll
    for (int j = 0; j < 8; j++) {
      int idx = base + j;
      if (idx < 442368) winb[idx] = f2bf(w_in[idx]);
      else              woutb[idx - 442368] = f2bf(w_out[idx - 442368]);
    }
  }
}

// ---------------- MFMA GEMM: out[M,.] = A[M,K](lda)*Bw[N,K](ldb)^T + bias --
// 128x128 tile, BK=64, 4 waves (2x2), 16x16x32 bf16 MFMA, padded LDS. VERIFIED.
template<bool OUT_F32, bool QSCALE>
__global__ __launch_bounds__(256) void gemm_kernel(
    const u16* __restrict__ A, int lda,
    const u16* __restrict__ Bw, int ldb,
    const float* __restrict__ bias, void* __restrict__ outp, int ldc, int K)
{
  __shared__ __attribute__((aligned(16))) u16 As[128 * 72];
  __shared__ __attribute__((aligned(16))) u16 Bs[128 * 72];
  int t = threadIdx.x;
  int lane = t & 63, wv = t >> 6;
  int g = lane >> 4, cl = lane & 15;
  int row0 = blockIdx.x * 128, col0 = blockIdx.y * 128;
  int wm = (wv >> 1) * 64, wn = (wv & 1) * 64;
  f32x4 acc[4][4];
  #pragma unroll
  for (int i = 0; i < 4; i++)
    #pragma unroll
    for (int j = 0; j < 4; j++) acc[i][j] = (f32x4){0.f, 0.f, 0.f, 0.f};

  for (int k0 = 0; k0 < K; k0 += 64) {
    __syncthreads();
    #pragma unroll
    for (int j = 0; j < 4; j++) {
      int i = t + 256 * j;
      int r = i >> 3, ch = i & 7;
      *(uint4*)(&As[r * 72 + ch * 8]) =
          *(const uint4*)(A + (size_t)(row0 + r) * lda + k0 + ch * 8);
      *(uint4*)(&Bs[r * 72 + ch * 8]) =
          *(const uint4*)(Bw + (size_t)(col0 + r) * ldb + k0 + ch * 8);
    }
    __syncthreads();
    #pragma unroll
    for (int kh = 0; kh < 2; kh++) {
      short8 af[4], bfr[4];
      #pragma unroll
      for (int s = 0; s < 4; s++) {
        af[s]  = *(const short8*)(&As[(wm + s * 16 + cl) * 72 + kh * 32 + g * 8]);
        bfr[s] = *(const short8*)(&Bs[(wn + s * 16 + cl) * 72 + kh * 32 + g * 8]);
      }
      #pragma unroll
      for (int i = 0; i < 4; i++)
        #pragma unroll
        for (int j = 0; j < 4; j++)
          acc[i][j] = mfma_bf16(af[i], bfr[j], acc[i][j]);
    }
  }
  // epilogue: C/D layout col=lane&15, row=4*(lane>>4)+r  [HW-verified R4]
  #pragma unroll
  for (int i = 0; i < 4; i++) {
    #pragma unroll
    for (int j = 0; j < 4; j++) {
      int colb = col0 + wn + j * 16 + cl;
      float bv = bias[colb];
      #pragma unroll
      for (int r = 0; r < 4; r++) {
        int rowb = row0 + wm + i * 16 + g * 4 + r;
        float v = acc[i][j][r] + bv;
        if (QSCALE) { if (colb < 384) v *= 0.125f; }   // fold 1/sqrt(D) into Q
        if (OUT_F32) ((float*)outp)[(size_t)rowb * ldc + colb] = v;
        else ((u16*)outp)[(size_t)rowb * ldc + colb] = f2bf(v);
      }
    }
  }
}

// ---------------- pipelined barrier-free swapped-QK^T attention ------------
// Block = (b, h, 16 q-rows), 256 threads / 4 waves; wave wv owns key quarter
// [wv*256, +256) in 8 tiles of 32 keys. Software pipeline per tile:
//   issue V/K/pos loads for tile it+1 (regs) -> compute tile it (QK^T MFMA,
//   packed-f32 Chebyshev bias, defer-max softmax, PV MFMA from vsmem) ->
//   ds_write V(it+1) AFTER PV's ds_reads (in-wave DS ordering, no barriers).
// End: per-lane l reduce, 4-quarter merge via LDS overlay (R4/R8-verified).
__global__ __launch_bounds__(256) void attn_swap5(
    const u16* __restrict__ qkv, const float* __restrict__ pos,
    const float* __restrict__ bcf, const float* __restrict__ ccf,
    u16* __restrict__ obuf)
{
  __shared__ __attribute__((aligned(16))) u16 vsmem[4][64][40];  // 20480 B

  // XCD-aware remap: all 64 q-strips of one (b,h) share bid%8 -> same XCD L2.
  int bid = blockIdx.x;                       // 3072 = 8 * 384
  int xslot = bid & 7, rest = bid >> 3;
  int qt16 = rest & 63, gdiv = rest >> 6;     // gdiv in [0,6)
  int g48 = gdiv * 8 + xslot;                 // (b*6 + h) in [0,48)
  int b = g48 / 6, h = g48 - b * 6;

  int t = threadIdx.x, lane = t & 63, wv = t >> 6;   // wv = key quarter
  int g = lane >> 4, cl = lane & 15;

  float bc[15], cc[15];                        // block-uniform
  #pragma unroll
  for (int i = 0; i < 15; i++) { bc[i] = bcf[h * 15 + i]; cc[i] = ccf[h * 15 + i]; }

  // Q B-frag (col=cl=q, k=dim 8g+j); Q pre-scaled by 1/8 in GEMM1
  int qrow = qt16 * 16 + cl;
  const u16* qbase = qkv + (size_t)(b * 1024 + qrow) * 1152 + h * 64;
  short8 qf0 = *(const short8*)(qbase + g * 8);
  short8 qf1 = *(const short8*)(qbase + 32 + g * 8);
  float qx = pos[(size_t)(b * 1024 + qrow) * 2 + 0];
  float qy = pos[(size_t)(b * 1024 + qrow) * 2 + 1];

  f32x4 oa[4];
  #pragma unroll
  for (int d = 0; d < 4; d++) oa[d] = (f32x4){0.f, 0.f, 0.f, 0.f};
  float m_own = -1e30f, l_own = 0.f;           // q=cl; l is PER-LANE partial

  const u16* kb = qkv + (size_t)b * 1024 * 1152 + 384 + h * 64;
  int kappa = lane & 31, dh = lane >> 5;       // V-stage identity
  const u16* vb = qkv + (size_t)b * 1024 * 1152 + 768 + h * 64 + dh * 32;
  const float* pb = pos + (size_t)b * 2048;

  // key kappa(=16s+4G+r) -> physical slot 8G+4s+r (matches P frag order)
  int pcol = (kappa & 3) | ((kappa & 0x0C) << 1) | ((kappa & 0x10) >> 2);
  u16* vdst = &vsmem[wv][dh * 32][0] + pcol;   // row stride 40 u16

  // u32 element offsets (uniform bases), advanced per tile
  u32 koff = (u32)(wv * 256 + cl) * 1152;
  u32 voff = (u32)(wv * 256 + kappa) * 1152;
  u32 poff = (u32)(wv * 256 + 4 * g) * 2;

  #define LOADV(d0,d1,d2,d3, off) { const u16* vr = vb + (off); \
      d0 = *(const uint4*)(vr); d1 = *(const uint4*)(vr + 8); \
      d2 = *(const uint4*)(vr + 16); d3 = *(const uint4*)(vr + 24); }
  #define LOADK(ka0,ka1,kb0,kb1, off) { \
      const u16* kr0 = kb + (off); const u16* kr1 = kr0 + 16 * 1152; \
      ka0 = *(const short8*)(kr0 + g * 8); ka1 = *(const short8*)(kr0 + 32 + g * 8); \
      kb0 = *(const short8*)(kr1 + g * 8); kb1 = *(const short8*)(kr1 + 32 + g * 8); }
  #define LOADP(pa0,pb0,pa1,pb1, off) { \
      pa0 = *(const float4*)(pb + (off));      pb0 = *(const float4*)(pb + (off) + 4); \
      pa1 = *(const float4*)(pb + (off) + 32); pb1 = *(const float4*)(pb + (off) + 36); }
  #define STAGE(d0,d1,d2,d3) { \
      vdst[ 0*40]=(u16)(d0.x); vdst[ 1*40]=(u16)(d0.x>>16); \
      vdst[ 2*40]=(u16)(d0.y); vdst[ 3*40]=(u16)(d0.y>>16); \
      vdst[ 4*40]=(u16)(d0.z); vdst[ 5*40]=(u16)(d0.z>>16); \
      vdst[ 6*40]=(u16)(d0.w); vdst[ 7*40]=(u16)(d0.w>>16); \
      vdst[ 8*40]=(u16)(d1.x); vdst[ 9*40]=(u16)(d1.x>>16); \
      vdst[10*40]=(u16)(d1.y); vdst[11*40]=(u16)(d1.y>>16); \
      vdst[12*40]=(u16)(d1.z); vdst[13*40]=(u16)(d1.z>>16); \
      vdst[14*40]=(u16)(d1.w); vdst[15*40]=(u16)(d1.w>>16); \
      vdst[16*40]=(u16)(d2.x); vdst[17*40]=(u16)(d2.x>>16); \
      vdst[18*40]=(u16)(d2.y); vdst[19*40]=(u16)(d2.y>>16); \
      vdst[20*40]=(u16)(d2.z); vdst[21*40]=(u16)(d2.z>>16); \
      vdst[22*40]=(u16)(d2.w); vdst[23*40]=(u16)(d2.w>>16); \
      vdst[24*40]=(u16)(d3.x); vdst[25*40]=(u16)(d3.x>>16); \
      vdst[26*40]=(u16)(d3.y); vdst[27*40]=(u16)(d3.y>>16); \
      vdst[28*40]=(u16)(d3.z); vdst[29*40]=(u16)(d3.z>>16); \
      vdst[30*40]=(u16)(d3.w); vdst[31*40]=(u16)(d3.w>>16); }

  // ---- prologue: tile 0 into regs; stage V(0) ----
  uint4 cv0, cv1, cv2, cv3; short8 ck00, ck01, ck10, ck11;
  float4 cp00, cp01, cp10, cp11;
  LOADV(cv0, cv1, cv2, cv3, voff);
  LOADK(ck00, ck01, ck10, ck11, koff);
  LOADP(cp00, cp01, cp10, cp11, poff);
  STAGE(cv0, cv1, cv2, cv3);
  voff += 32 * 1152; koff += 32 * 1152; poff += 64;

  #pragma unroll
  for (int it = 0; it < 8; it++) {
    // ---- issue prefetch for tile it+1 (no wait) ----
    uint4 nv0, nv1, nv2, nv3; short8 nk00, nk01, nk10, nk11;
    float4 np00, np01, np10, np11;
    if (it < 7) {
      LOADV(nv0, nv1, nv2, nv3, voff);
      LOADK(nk00, nk01, nk10, nk11, koff);
      LOADP(np00, np01, np10, np11, poff);
      voff += 32 * 1152; koff += 32 * 1152; poff += 64;
    }
    // ---- swapped QK^T from registers: sk[ks][r] = S[key slot][q=cl] ----
    f32x4 sk[2];
    {
      f32x4 z = (f32x4){0.f, 0.f, 0.f, 0.f};
      z = mfma_bf16(ck00, qf0, z); z = mfma_bf16(ck01, qf1, z);
      sk[0] = z;
      z = (f32x4){0.f, 0.f, 0.f, 0.f};
      z = mfma_bf16(ck10, qf0, z); z = mfma_bf16(ck11, qf1, z);
      sk[1] = z;
    }
    // ---- packed-f32 Chebyshev polar bias (ks=0,1 in f32x2 lanes) ----
    {
      float kx0[4] = {cp00.x, cp00.z, cp01.x, cp01.z};
      float ky0[4] = {cp00.y, cp00.w, cp01.y, cp01.w};
      float kx1[4] = {cp10.x, cp10.z, cp11.x, cp11.z};
      float ky1[4] = {cp10.y, cp10.w, cp11.y, cp11.w};
      #pragma unroll
      for (int r = 0; r < 4; r++) {
        f32x2 dx = {qx - kx0[r], qx - kx1[r]};
        f32x2 dy = {qy - ky0[r], qy - ky1[r]};
        f32x2 r2 = dx * dx + dy * dy;
        float ir0 = (r2.x > 0.f) ? __builtin_amdgcn_rsqf(r2.x) : 0.f;
        float ir1 = (r2.y > 0.f) ? __builtin_amdgcn_rsqf(r2.y) : 0.f;
        f32x2 ir = {ir0, ir1};
        f32x2 rr = r2 * ir;
        f32x2 c1 = {(r2.x > 0.f) ? dx.x * ir0 : 1.f,
                    (r2.y > 0.f) ? dx.y * ir1 : 1.f};
        f32x2 s1 = dy * ir;
        f32x2 tc = c1 + c1;
        f32x2 c2 = tc * c1 - 1.f, s2 = tc * s1;
        f32x2 c3 = tc * c2 - c1,  s3 = tc * s2 - s1;
        f32x2 c4 = tc * c3 - c2,  s4 = tc * s3 - s2;
        f32x2 a0 = bc[0] + bc[1]*c1 + bc[2]*c2 + bc[3]*c3 + bc[4]*c4
                 + cc[1]*s1 + cc[2]*s2 + cc[3]*s3 + cc[4]*s4;
        f32x2 a1 = bc[5] + bc[6]*c1 + bc[7]*c2 + bc[8]*c3 + bc[9]*c4
                 + cc[6]*s1 + cc[7]*s2 + cc[8]*s3 + cc[9]*s4;
        f32x2 a2 = bc[10] + bc[11]*c1 + bc[12]*c2 + bc[13]*c3 + bc[14]*c4
                 + cc[11]*s1 + cc[12]*s2 + cc[13]*s3 + cc[14]*s4;
        f32x2 sv = a0 + rr * (a1 + rr * a2);
        sk[0][r] += sv.x;
        sk[1][r] += sv.y;
      }
    }
    // ---- defer-max online softmax: common path = no cross-lane ops ----
    float tmax = -1e30f;
    #pragma unroll
    for (int ks = 0; ks < 2; ks++)
      #pragma unroll
      for (int r = 0; r < 4; r++) tmax = fmaxf(tmax, sk[ks][r]);
    if (!__all((int)(tmax <= m_own + 8.f))) {
      tmax = fmaxf(tmax, __shfl_xor(tmax, 16));
      tmax = fmaxf(tmax, __shfl_xor(tmax, 32));
      float mn = fmaxf(m_own, tmax);
      float sc = __builtin_amdgcn_exp2f((m_own - mn) * 1.44269504f);
      m_own = mn;
      l_own *= sc;
      #pragma unroll
      for (int r = 0; r < 4; r++) {
        float scr = __shfl(sc, 4 * g + r);     // rescale rows q=4g+r
        #pragma unroll
        for (int d = 0; d < 4; d++) oa[d][r] *= scr;
      }
    }
    float psum = 0.f;
    #pragma unroll
    for (int ks = 0; ks < 2; ks++)
      #pragma unroll
      for (int r = 0; r < 4; r++) {
        float p = __builtin_amdgcn_exp2f((sk[ks][r] - m_own) * 1.44269504f);
        psum += p; sk[ks][r] = p;              // bounded by e^8
      }
    l_own += psum;                             // per-lane partial
    // P A-frag: element j holds key 16*(j>>2) + 4g + (j&3)
    union { u32 w[4]; short8 s8; } pk;
    pk.w[0] = cvtpk(sk[0][0], sk[0][1]); pk.w[1] = cvtpk(sk[0][2], sk[0][3]);
    pk.w[2] = cvtpk(sk[1][0], sk[1][1]); pk.w[3] = cvtpk(sk[1][2], sk[1][3]);
    // ---- PV MFMA: B-frag = vsmem rows (permuted slots match A) ----
    #pragma unroll
    for (int d = 0; d < 4; d++) {
      short8 vf = *(const short8*)(&vsmem[wv][d * 16 + cl][g * 8]);
      oa[d] = mfma_bf16(pk.s8, vf, oa[d]);
    }
    // ---- stage V(it+1) AFTER PV's ds_reads (in-wave order); swap regs ----
    if (it < 7) {
      STAGE(nv0, nv1, nv2, nv3);
      ck00 = nk00; ck01 = nk01; ck10 = nk10; ck11 = nk11;
      cp00 = np00; cp01 = np01; cp10 = np10; cp11 = np11;
    }
  }
  #undef LOADV
  #undef LOADK
  #undef LOADP
  #undef STAGE
  // ---- row-reduce the per-lane partial l (once) ----
  l_own += __shfl_xor(l_own, 16);
  l_own += __shfl_xor(l_own, 32);
  __syncthreads();                             // all waves done with vsmem
  // ---- merge the 4 key quarters; overlay vsmem (o1: 12288 B, ml at tail) --
  float* o1 = (float*)&vsmem[0][0][0];         // [3][16][64] f32
  float* ml = (float*)((char*)&vsmem[0][0][0] + 19968);   // m[4][16], l[4][16]
  if (lane < 16) { ml[wv * 16 + lane] = m_own; ml[64 + wv * 16 + lane] = l_own; }
  if (wv > 0) {
    #pragma unroll
    for (int r = 0; r < 4; r++) {
      int row = 4 * g + r;
      #pragma unroll
      for (int d = 0; d < 4; d++)
        o1[((wv - 1) * 16 + row) * 64 + d * 16 + cl] = oa[d][r];
    }
  }
  __syncthreads();
  if (wv == 0) {
    float m1 = ml[16 + cl], m2 = ml[32 + cl], m3 = ml[48 + cl];
    float l1 = ml[80 + cl], l2 = ml[96 + cl], l3 = ml[112 + cl];
    float M  = fmaxf(fmaxf(m_own, m1), fmaxf(m2, m3));
    float f0 = __builtin_amdgcn_exp2f((m_own - M) * 1.44269504f);
    float f1 = __builtin_amdgcn_exp2f((m1 - M) * 1.44269504f);
    float f2 = __builtin_amdgcn_exp2f((m2 - M) * 1.44269504f);
    float f3 = __builtin_amdgcn_exp2f((m3 - M) * 1.44269504f);
    float linv = __builtin_amdgcn_rcpf(l_own * f0 + l1 * f1 + l2 * f2 + l3 * f3);
    #pragma unroll
    for (int r = 0; r < 4; r++) {
      int row = 4 * g + r;
      float f0r = __shfl(f0, row), f1r = __shfl(f1, row);
      float f2r = __shfl(f2, row), f3r = __shfl(f3, row);
      float invr = __shfl(linv, row);
      int qr = qt16 * 16 + row;
      #pragma unroll
      for (int d = 0; d < 4; d++) {
        float val = (oa[d][r] * f0r
                   + o1[(0 * 16 + row) * 64 + d * 16 + cl] * f1r
                   + o1[(1 * 16 + row) * 64 + d * 16 + cl] * f2r
                   + o1[(2 * 16 + row) * 64 + d * 16 + cl] * f3r) * invr;
        obuf[(size_t)(b * 1024 + qr) * 384 + h * 64 + d * 16 + cl] = f2bf(val);
      }
    }
  }
}

// ---------------- launch ---------------------------------------------------
extern "C" void kernel_launch(void* const* d_in, const int* in_sizes, int n_in,
                              void* d_out, int out_size, void* d_ws, size_t ws_size,
                              hipStream_t stream) {
  const float* x      = (const float*)d_in[0];
  const float* pos    = (const float*)d_in[1];
  const float* w_norm = (const float*)d_in[2];
  const float* w_in   = (const float*)d_in[3];
  const float* b_in   = (const float*)d_in[4];
  const float* w_out  = (const float*)d_in[5];
  const float* b_out  = (const float*)d_in[6];
  const float* b_coef = (const float*)d_in[7];
  const float* c_coef = (const float*)d_in[8];

  char* ws = (char*)d_ws;
  // ws layout (25.1 MB):
  //   [0, 6291456)        xn (bf16 8192x384); obuf overlays it (xn dead after GEMM1)
  //   [6291456, 7176192)  winb (bf16 1152x384)
  //   [7176192, 7471104)  woutb (bf16 384x384)
  //   [7471104, 26345472) qkv (bf16 8192x1152), Q pre-scaled by 1/8
  u16* xn    = (u16*)(ws + 0);
  u16* obuf  = (u16*)(ws + 0);          // overlays xn
  u16* winb  = (u16*)(ws + 6291456);
  u16* woutb = (u16*)(ws + 7176192);
  u16* qkvb  = (u16*)(ws + 7471104);

  prep_kernel<<<2336, 256, 0, stream>>>(x, w_norm, w_in, w_out, xn, winb, woutb);
  gemm_kernel<false, true><<<dim3(64, 9), 256, 0, stream>>>(
      xn, 384, winb, 384, b_in, qkvb, 1152, 384);
  attn_swap5<<<3072, 256, 0, stream>>>(qkvb, pos, b_coef, c_coef, obuf);
  gemm_kernel<true, false><<<dim3(64, 3), 256, 0, stream>>>(
      obuf, 384, woutb, 384, b_out, (float*)d_out, 384, 384);
}

// Round 14
// 146.852 us; speedup vs baseline: 1.0659x; 1.0001x over previous
//
#include <hip/hip_runtime.h>

// Problem: B=8, L=1024, C=384, H=6, D=64, K=2(radial), N=4(angular)
// R12: MFMA GEMMs (verified) + barrier-free swapped-QK^T attention with
//      software-pipelined tile loop (prefetch V/K/pos into regs, T14) and
//      packed-f32 (v_pk_fma) Chebyshev bias across the two key groups.
typedef unsigned int  u32;
typedef unsigned short u16;
typedef __attribute__((ext_vector_type(8))) short short8;   // 8 bf16
typedef __attribute__((ext_vector_type(4))) float f32x4;
typedef __attribute__((ext_vector_type(2))) float f32x2;

__device__ __forceinline__ u16 f2bf(float x) {
  union { float f; u32 u; } un; un.f = x;
  u32 r = un.u + 0x7FFFu + ((un.u >> 16) & 1u);   // RNE
  return (u16)(r >> 16);
}
__device__ __forceinline__ u32 cvtpk(float lo, float hi) {   // 2xf32 -> packed bf16
  u32 r;
  asm("v_cvt_pk_bf16_f32 %0, %1, %2" : "=v"(r) : "v"(lo), "v"(hi));
  return r;
}
__device__ __forceinline__ f32x4 mfma_bf16(short8 a, short8 b, f32x4 c) {
  return __builtin_amdgcn_mfma_f32_16x16x32_bf16(a, b, c, 0, 0, 0);
}

// ---------------- prep: RMSNorm -> xn(bf16), convert w_in/w_out -> bf16 ----
__global__ __launch_bounds__(256) void prep_kernel(
    const float* __restrict__ x, const float* __restrict__ w_norm,
    const float* __restrict__ w_in, const float* __restrict__ w_out,
    u16* __restrict__ xn, u16* __restrict__ winb, u16* __restrict__ woutb)
{
  int blk = blockIdx.x, t = threadIdx.x;
  if (blk < 2048) {               // 8192 rows, 4 rows/block (1 per wave)
    int wv = t >> 6, lane = t & 63;
    int row = blk * 4 + wv;
    const float* xr = x + (size_t)row * 384;
    float v[6]; float ss = 0.f;
    #pragma unroll
    for (int i = 0; i < 6; i++) { v[i] = xr[lane + 64 * i]; ss += v[i] * v[i]; }
    #pragma unroll
    for (int off = 32; off > 0; off >>= 1) ss += __shfl_xor(ss, off);
    float rs = __builtin_amdgcn_rsqf(ss * (1.0f / 384.0f) + 1e-5f);
    #pragma unroll
    for (int i = 0; i < 6; i++) {
      float xv = v[i] * rs * w_norm[lane + 64 * i];
      xn[(size_t)row * 384 + lane + 64 * i] = f2bf(xv);
    }
  } else {                        // weight conversion: 442368 + 147456
    int base = (blk - 2048) * 2048 + t * 8;
    #pragma unroll
    for (int j = 0; j < 8; j++) {
      int idx = base + j;
      if (idx < 442368) winb[idx] = f2bf(w_in[idx]);
      else              woutb[idx - 442368] = f2bf(w_out[idx - 442368]);
    }
  }
}

// ---------------- MFMA GEMM: out[M,.] = A[M,K](lda)*Bw[N,K](ldb)^T + bias --
// 128x128 tile, BK=64, 4 waves (2x2), 16x16x32 bf16 MFMA, padded LDS. VERIFIED.
template<bool OUT_F32, bool QSCALE>
__global__ __launch_bounds__(256) void gemm_kernel(
    const u16* __restrict__ A, int lda,
    const u16* __restrict__ Bw, int ldb,
    const float* __restrict__ bias, void* __restrict__ outp, int ldc, int K)
{
  __shared__ __attribute__((aligned(16))) u16 As[128 * 72];
  __shared__ __attribute__((aligned(16))) u16 Bs[128 * 72];
  int t = threadIdx.x;
  int lane = t & 63, wv = t >> 6;
  int g = lane >> 4, cl = lane & 15;
  int row0 = blockIdx.x * 128, col0 = blockIdx.y * 128;
  int wm = (wv >> 1) * 64, wn = (wv & 1) * 64;
  f32x4 acc[4][4];
  #pragma unroll
  for (int i = 0; i < 4; i++)
    #pragma unroll
    for (int j = 0; j < 4; j++) acc[i][j] = (f32x4){0.f, 0.f, 0.f, 0.f};

  for (int k0 = 0; k0 < K; k0 += 64) {
    __syncthreads();
    #pragma unroll
    for (int j = 0; j < 4; j++) {
      int i = t + 256 * j;
      int r = i >> 3, ch = i & 7;
      *(uint4*)(&As[r * 72 + ch * 8]) =
          *(const uint4*)(A + (size_t)(row0 + r) * lda + k0 + ch * 8);
      *(uint4*)(&Bs[r * 72 + ch * 8]) =
          *(const uint4*)(Bw + (size_t)(col0 + r) * ldb + k0 + ch * 8);
    }
    __syncthreads();
    #pragma unroll
    for (int kh = 0; kh < 2; kh++) {
      short8 af[4], bfr[4];
      #pragma unroll
      for (int s = 0; s < 4; s++) {
        af[s]  = *(const short8*)(&As[(wm + s * 16 + cl) * 72 + kh * 32 + g * 8]);
        bfr[s] = *(const short8*)(&Bs[(wn + s * 16 + cl) * 72 + kh * 32 + g * 8]);
      }
      #pragma unroll
      for (int i = 0; i < 4; i++)
        #pragma unroll
        for (int j = 0; j < 4; j++)
          acc[i][j] = mfma_bf16(af[i], bfr[j], acc[i][j]);
    }
  }
  // epilogue: C/D layout col=lane&15, row=4*(lane>>4)+r  [HW-verified R4]
  #pragma unroll
  for (int i = 0; i < 4; i++) {
    #pragma unroll
    for (int j = 0; j < 4; j++) {
      int colb = col0 + wn + j * 16 + cl;
      float bv = bias[colb];
      #pragma unroll
      for (int r = 0; r < 4; r++) {
        int rowb = row0 + wm + i * 16 + g * 4 + r;
        float v = acc[i][j][r] + bv;
        if (QSCALE) { if (colb < 384) v *= 0.125f; }   // fold 1/sqrt(D) into Q
        if (OUT_F32) ((float*)outp)[(size_t)rowb * ldc + colb] = v;
        else ((u16*)outp)[(size_t)rowb * ldc + colb] = f2bf(v);
      }
    }
  }
}

// ---------------- pipelined barrier-free swapped-QK^T attention ------------
// Block = (b, h, 16 q-rows), 256 threads / 4 waves; wave wv owns key quarter
// [wv*256, +256) in 8 tiles of 32 keys. Software pipeline per tile:
//   issue V/K/pos loads for tile it+1 (regs) -> compute tile it (QK^T MFMA,
//   packed-f32 Chebyshev bias, defer-max softmax, PV MFMA from vsmem) ->
//   ds_write V(it+1) AFTER PV's ds_reads (in-wave DS ordering, no barriers).
// End: per-lane l reduce, 4-quarter merge via LDS overlay (R4/R8-verified).
__global__ __launch_bounds__(256) void attn_swap5(
    const u16* __restrict__ qkv, const float* __restrict__ pos,
    const float* __restrict__ bcf, const float* __restrict__ ccf,
    u16* __restrict__ obuf)
{
  __shared__ __attribute__((aligned(16))) u16 vsmem[4][64][40];  // 20480 B

  // XCD-aware remap: all 64 q-strips of one (b,h) share bid%8 -> same XCD L2.
  int bid = blockIdx.x;                       // 3072 = 8 * 384
  int xslot = bid & 7, rest = bid >> 3;
  int qt16 = rest & 63, gdiv = rest >> 6;     // gdiv in [0,6)
  int g48 = gdiv * 8 + xslot;                 // (b*6 + h) in [0,48)
  int b = g48 / 6, h = g48 - b * 6;

  int t = threadIdx.x, lane = t & 63, wv = t >> 6;   // wv = key quarter
  int g = lane >> 4, cl = lane & 15;

  float bc[15], cc[15];                        // block-uniform
  #pragma unroll
  for (int i = 0; i < 15; i++) { bc[i] = bcf[h * 15 + i]; cc[i] = ccf[h * 15 + i]; }

  // Q B-frag (col=cl=q, k=dim 8g+j); Q pre-scaled by 1/8 in GEMM1
  int qrow = qt16 * 16 + cl;
  const u16* qbase = qkv + (size_t)(b * 1024 + qrow) * 1152 + h * 64;
  short8 qf0 = *(const short8*)(qbase + g * 8);
  short8 qf1 = *(const short8*)(qbase + 32 + g * 8);
  float qx = pos[(size_t)(b * 1024 + qrow) * 2 + 0];
  float qy = pos[(size_t)(b * 1024 + qrow) * 2 + 1];

  f32x4 oa[4];
  #pragma unroll
  for (int d = 0; d < 4; d++) oa[d] = (f32x4){0.f, 0.f, 0.f, 0.f};
  float m_own = -1e30f, l_own = 0.f;           // q=cl; l is PER-LANE partial

  const u16* kb = qkv + (size_t)b * 1024 * 1152 + 384 + h * 64;
  int kappa = lane & 31, dh = lane >> 5;       // V-stage identity
  const u16* vb = qkv + (size_t)b * 1024 * 1152 + 768 + h * 64 + dh * 32;
  const float* pb = pos + (size_t)b * 2048;

  // key kappa(=16s+4G+r) -> physical slot 8G+4s+r (matches P frag order)
  int pcol = (kappa & 3) | ((kappa & 0x0C) << 1) | ((kappa & 0x10) >> 2);
  u16* vdst = &vsmem[wv][dh * 32][0] + pcol;   // row stride 40 u16

  // u32 element offsets (uniform bases), advanced per tile
  u32 koff = (u32)(wv * 256 + cl) * 1152;
  u32 voff = (u32)(wv * 256 + kappa) * 1152;
  u32 poff = (u32)(wv * 256 + 4 * g) * 2;

  #define LOADV(d0,d1,d2,d3, off) { const u16* vr = vb + (off); \
      d0 = *(const uint4*)(vr); d1 = *(const uint4*)(vr + 8); \
      d2 = *(const uint4*)(vr + 16); d3 = *(const uint4*)(vr + 24); }
  #define LOADK(ka0,ka1,kb0,kb1, off) { \
      const u16* kr0 = kb + (off); const u16* kr1 = kr0 + 16 * 1152; \
      ka0 = *(const short8*)(kr0 + g * 8); ka1 = *(const short8*)(kr0 + 32 + g * 8); \
      kb0 = *(const short8*)(kr1 + g * 8); kb1 = *(const short8*)(kr1 + 32 + g * 8); }
  #define LOADP(pa0,pb0,pa1,pb1, off) { \
      pa0 = *(const float4*)(pb + (off));      pb0 = *(const float4*)(pb + (off) + 4); \
      pa1 = *(const float4*)(pb + (off) + 32); pb1 = *(const float4*)(pb + (off) + 36); }
  #define STAGE(d0,d1,d2,d3) { \
      vdst[ 0*40]=(u16)(d0.x); vdst[ 1*40]=(u16)(d0.x>>16); \
      vdst[ 2*40]=(u16)(d0.y); vdst[ 3*40]=(u16)(d0.y>>16); \
      vdst[ 4*40]=(u16)(d0.z); vdst[ 5*40]=(u16)(d0.z>>16); \
      vdst[ 6*40]=(u16)(d0.w); vdst[ 7*40]=(u16)(d0.w>>16); \
      vdst[ 8*40]=(u16)(d1.x); vdst[ 9*40]=(u16)(d1.x>>16); \
      vdst[10*40]=(u16)(d1.y); vdst[11*40]=(u16)(d1.y>>16); \
      vdst[12*40]=(u16)(d1.z); vdst[13*40]=(u16)(d1.z>>16); \
      vdst[14*40]=(u16)(d1.w); vdst[15*40]=(u16)(d1.w>>16); \
      vdst[16*40]=(u16)(d2.x); vdst[17*40]=(u16)(d2.x>>16); \
      vdst[18*40]=(u16)(d2.y); vdst[19*40]=(u16)(d2.y>>16); \
      vdst[20*40]=(u16)(d2.z); vdst[21*40]=(u16)(d2.z>>16); \
      vdst[22*40]=(u16)(d2.w); vdst[23*40]=(u16)(d2.w>>16); \
      vdst[24*40]=(u16)(d3.x); vdst[25*40]=(u16)(d3.x>>16); \
      vdst[26*40]=(u16)(d3.y); vdst[27*40]=(u16)(d3.y>>16); \
      vdst[28*40]=(u16)(d3.z); vdst[29*40]=(u16)(d3.z>>16); \
      vdst[30*40]=(u16)(d3.w); vdst[31*40]=(u16)(d3.w>>16); }

  // ---- prologue: tile 0 into regs; stage V(0) ----
  uint4 cv0, cv1, cv2, cv3; short8 ck00, ck01, ck10, ck11;
  float4 cp00, cp01, cp10, cp11;
  LOADV(cv0, cv1, cv2, cv3, voff);
  LOADK(ck00, ck01, ck10, ck11, koff);
  LOADP(cp00, cp01, cp10, cp11, poff);
  STAGE(cv0, cv1, cv2, cv3);
  voff += 32 * 1152; koff += 32 * 1152; poff += 64;

  #pragma unroll
  for (int it = 0; it < 8; it++) {
    // ---- issue prefetch for tile it+1 (no wait) ----
    uint4 nv0, nv1, nv2, nv3; short8 nk00, nk01, nk10, nk11;
    float4 np00, np01, np10, np11;
    if (it < 7) {
      LOADV(nv0, nv1, nv2, nv3, voff);
      LOADK(nk00, nk01, nk10, nk11, koff);
      LOADP(np00, np01, np10, np11, poff);
      voff += 32 * 1152; koff += 32 * 1152; poff += 64;
    }
    // ---- swapped QK^T from registers: sk[ks][r] = S[key slot][q=cl] ----
    f32x4 sk[2];
    {
      f32x4 z = (f32x4){0.f, 0.f, 0.f, 0.f};
      z = mfma_bf16(ck00, qf0, z); z = mfma_bf16(ck01, qf1, z);
      sk[0] = z;
      z = (f32x4){0.f, 0.f, 0.f, 0.f};
      z = mfma_bf16(ck10, qf0, z); z = mfma_bf16(ck11, qf1, z);
      sk[1] = z;
    }
    // ---- packed-f32 Chebyshev polar bias (ks=0,1 in f32x2 lanes) ----
    {
      float kx0[4] = {cp00.x, cp00.z, cp01.x, cp01.z};
      float ky0[4] = {cp00.y, cp00.w, cp01.y, cp01.w};
      float kx1[4] = {cp10.x, cp10.z, cp11.x, cp11.z};
      float ky1[4] = {cp10.y, cp10.w, cp11.y, cp11.w};
      #pragma unroll
      for (int r = 0; r < 4; r++) {
        f32x2 dx = {qx - kx0[r], qx - kx1[r]};
        f32x2 dy = {qy - ky0[r], qy - ky1[r]};
        f32x2 r2 = dx * dx + dy * dy;
        float ir0 = (r2.x > 0.f) ? __builtin_amdgcn_rsqf(r2.x) : 0.f;
        float ir1 = (r2.y > 0.f) ? __builtin_amdgcn_rsqf(r2.y) : 0.f;
        f32x2 ir = {ir0, ir1};
        f32x2 rr = r2 * ir;
        f32x2 c1 = {(r2.x > 0.f) ? dx.x * ir0 : 1.f,
                    (r2.y > 0.f) ? dx.y * ir1 : 1.f};
        f32x2 s1 = dy * ir;
        f32x2 tc = c1 + c1;
        f32x2 c2 = tc * c1 - 1.f, s2 = tc * s1;
        f32x2 c3 = tc * c2 - c1,  s3 = tc * s2 - s1;
        f32x2 c4 = tc * c3 - c2,  s4 = tc * s3 - s2;
        f32x2 a0 = bc[0] + bc[1]*c1 + bc[2]*c2 + bc[3]*c3 + bc[4]*c4
                 + cc[1]*s1 + cc[2]*s2 + cc[3]*s3 + cc[4]*s4;
        f32x2 a1 = bc[5] + bc[6]*c1 + bc[7]*c2 + bc[8]*c3 + bc[9]*c4
                 + cc[6]*s1 + cc[7]*s2 + cc[8]*s3 + cc[9]*s4;
        f32x2 a2 = bc[10] + bc[11]*c1 + bc[12]*c2 + bc[13]*c3 + bc[14]*c4
                 + cc[11]*s1 + cc[12]*s2 + cc[13]*s3 + cc[14]*s4;
        f32x2 sv = a0 + rr * (a1 + rr * a2);
        sk[0][r] += sv.x;
        sk[1][r] += sv.y;
      }
    }
    // ---- defer-max online softmax: common path = no cross-lane ops ----
    float tmax = -1e30f;
    #pragma unroll
    for (int ks = 0; ks < 2; ks++)
      #pragma unroll
      for (int r = 0; r < 4; r++) tmax = fmaxf(tmax, sk[ks][r]);
    if (!__all((int)(tmax <= m_own + 8.f))) {
      tmax = fmaxf(tmax, __shfl_xor(tmax, 16));
      tmax = fmaxf(tmax, __shfl_xor(tmax, 32));
      float mn = fmaxf(m_own, tmax);
      float sc = __builtin_amdgcn_exp2f((m_own - mn) * 1.44269504f);
      m_own = mn;
      l_own *= sc;
      #pragma unroll
      for (int r = 0; r < 4; r++) {
        float scr = __shfl(sc, 4 * g + r);     // rescale rows q=4g+r
        #pragma unroll
        for (int d = 0; d < 4; d++) oa[d][r] *= scr;
      }
    }
    float psum = 0.f;
    #pragma unroll
    for (int ks = 0; ks < 2; ks++)
      #pragma unroll
      for (int r = 0; r < 4; r++) {
        float p = __builtin_amdgcn_exp2f((sk[ks][r] - m_own) * 1.44269504f);
        psum += p; sk[ks][r] = p;              // bounded by e^8
      }
    l_own += psum;                             // per-lane partial
    // P A-frag: element j holds key 16*(j>>2) + 4g + (j&3)
    union { u32 w[4]; short8 s8; } pk;
    pk.w[0] = cvtpk(sk[0][0], sk[0][1]); pk.w[1] = cvtpk(sk[0][2], sk[0][3]);
    pk.w[2] = cvtpk(sk[1][0], sk[1][1]); pk.w[3] = cvtpk(sk[1][2], sk[1][3]);
    // ---- PV MFMA: B-frag = vsmem rows (permuted slots match A) ----
    #pragma unroll
    for (int d = 0; d < 4; d++) {
      short8 vf = *(const short8*)(&vsmem[wv][d * 16 + cl][g * 8]);
      oa[d] = mfma_bf16(pk.s8, vf, oa[d]);
    }
    // ---- stage V(it+1) AFTER PV's ds_reads (in-wave order); swap regs ----
    if (it < 7) {
      STAGE(nv0, nv1, nv2, nv3);
      ck00 = nk00; ck01 = nk01; ck10 = nk10; ck11 = nk11;
      cp00 = np00; cp01 = np01; cp10 = np10; cp11 = np11;
    }
  }
  #undef LOADV
  #undef LOADK
  #undef LOADP
  #undef STAGE
  // ---- row-reduce the per-lane partial l (once) ----
  l_own += __shfl_xor(l_own, 16);
  l_own += __shfl_xor(l_own, 32);
  __syncthreads();                             // all waves done with vsmem
  // ---- merge the 4 key quarters; overlay vsmem (o1: 12288 B, ml at tail) --
  float* o1 = (float*)&vsmem[0][0][0];         // [3][16][64] f32
  float* ml = (float*)((char*)&vsmem[0][0][0] + 19968);   // m[4][16], l[4][16]
  if (lane < 16) { ml[wv * 16 + lane] = m_own; ml[64 + wv * 16 + lane] = l_own; }
  if (wv > 0) {
    #pragma unroll
    for (int r = 0; r < 4; r++) {
      int row = 4 * g + r;
      #pragma unroll
      for (int d = 0; d < 4; d++)
        o1[((wv - 1) * 16 + row) * 64 + d * 16 + cl] = oa[d][r];
    }
  }
  __syncthreads();
  if (wv == 0) {
    float m1 = ml[16 + cl], m2 = ml[32 + cl], m3 = ml[48 + cl];
    float l1 = ml[80 + cl], l2 = ml[96 + cl], l3 = ml[112 + cl];
    float M  = fmaxf(fmaxf(m_own, m1), fmaxf(m2, m3));
    float f0 = __builtin_amdgcn_exp2f((m_own - M) * 1.44269504f);
    float f1 = __builtin_amdgcn_exp2f((m1 - M) * 1.44269504f);
    float f2 = __builtin_amdgcn_exp2f((m2 - M) * 1.44269504f);
    float f3 = __builtin_amdgcn_exp2f((m3 - M) * 1.44269504f);
    float linv = __builtin_amdgcn_rcpf(l_own * f0 + l1 * f1 + l2 * f2 + l3 * f3);
    #pragma unroll
    for (int r = 0; r < 4; r++) {
      int row = 4 * g + r;
      float f0r = __shfl(f0, row), f1r = __shfl(f1, row);
      float f2r = __shfl(f2, row), f3r = __shfl(f3, row);
      float invr = __shfl(linv, row);
      int qr = qt16 * 16 + row;
      #pragma unroll
      for (int d = 0; d < 4; d++) {
        float val = (oa[d][r] * f0r
                   + o1[(0 * 16 + row) * 64 + d * 16 + cl] * f1r
                   + o1[(1 * 16 + row) * 64 + d * 16 + cl] * f2r
                   + o1[(2 * 16 + row) * 64 + d * 16 + cl] * f3r) * invr;
        obuf[(size_t)(b * 1024 + qr) * 384 + h * 64 + d * 16 + cl] = f2bf(val);
      }
    }
  }
}

// ---------------- launch ---------------------------------------------------
extern "C" void kernel_launch(void* const* d_in, const int* in_sizes, int n_in,
                              void* d_out, int out_size, void* d_ws, size_t ws_size,
                              hipStream_t stream) {
  const float* x      = (const float*)d_in[0];
  const float* pos    = (const float*)d_in[1];
  const float* w_norm = (const float*)d_in[2];
  const float* w_in   = (const float*)d_in[3];
  const float* b_in   = (const float*)d_in[4];
  const float* w_out  = (const float*)d_in[5];
  const float* b_out  = (const float*)d_in[6];
  const float* b_coef = (const float*)d_in[7];
  const float* c_coef = (const float*)d_in[8];

  char* ws = (char*)d_ws;
  // ws layout (25.1 MB):
  //   [0, 6291456)        xn (bf16 8192x384); obuf overlays it (xn dead after GEMM1)
  //   [6291456, 7176192)  winb (bf16 1152x384)
  //   [7176192, 7471104)  woutb (bf16 384x384)
  //   [7471104, 26345472) qkv (bf16 8192x1152), Q pre-scaled by 1/8
  u16* xn    = (u16*)(ws + 0);
  u16* obuf  = (u16*)(ws + 0);          // overlays xn
  u16* winb  = (u16*)(ws + 6291456);
  u16* woutb = (u16*)(ws + 7176192);
  u16* qkvb  = (u16*)(ws + 7471104);

  prep_kernel<<<2336, 256, 0, stream>>>(x, w_norm, w_in, w_out, xn, winb, woutb);
  gemm_kernel<false, true><<<dim3(64, 9), 256, 0, stream>>>(
      xn, 384, winb, 384, b_in, qkvb, 1152, 384);
  attn_swap5<<<3072, 256, 0, stream>>>(qkvb, pos, b_coef, c_coef, obuf);
  gemm_kernel<true, false><<<dim3(64, 3), 256, 0, stream>>>(
      obuf, 384, woutb, 384, b_out, (float*)d_out, 384, 384);
}